// Round 9
// baseline (421.052 us; speedup 1.0000x reference)
//
#include <hip/hip_runtime.h>

typedef __attribute__((ext_vector_type(8))) short short8v;
typedef __attribute__((ext_vector_type(4))) short short4v;
typedef __attribute__((ext_vector_type(4))) float floatx4;
typedef __attribute__((ext_vector_type(2))) int int2v;

#define S_    2048
#define DIM_  2048
#define NW_   6400   // wq 0..2047 | waq 2048..2079 | wak 2080..2111 | wk 2112..4159 | pad 4160..4351 | wv 4352..6399
#define VOFF_ 4352   // V region start (256-aligned so 256-wide tiles don't straddle)

#define ASG(p) ((__attribute__((address_space(1))) void*)(p))
#define ASL(p) ((__attribute__((address_space(3))) void*)(p))

__device__ __forceinline__ short f2bf(float f){
  union { float f; unsigned u; } c; c.f = f;
  unsigned u = c.u;
  unsigned r = (u + 0x7fffu + ((u >> 16) & 1u)) >> 16;
  return (short)r;
}
__device__ __forceinline__ float bf2f(short s){
  union { unsigned u; float f; } c; c.u = ((unsigned)(unsigned short)s) << 16;
  return c.f;
}

// ---------------- f32 -> bf16 convert (x) ----------------
__global__ __launch_bounds__(256) void cvt_k(const float* __restrict__ in,
                                             short* __restrict__ out, int n){
  int i = blockIdx.x*256 + threadIdx.x;
  int idx = i*4;
  if (idx >= n) return;
  floatx4 v = *(const floatx4*)(in + idx);
  short4v o;
  o[0]=f2bf(v[0]); o[1]=f2bf(v[1]); o[2]=f2bf(v[2]); o[3]=f2bf(v[3]);
  *(short4v*)(out + idx) = o;
}

// ---------------- all weights -> bf16 (grid 4096x5) ----------
__global__ __launch_bounds__(256)
void cvt_w(const float* wq, const float* waq, const float* wak,
           const float* wk, const float* wv, const float* wo,
           short* Wcat, short* wob){
  const float* src; short* dst; int n;
  int bx = blockIdx.x;
  switch (blockIdx.y){
    case 0: src=wq; dst=Wcat;                   n=4194304; break;
    case 1: src=wk; dst=Wcat+(size_t)2112*2048; n=4194304; break;
    case 2: src=wv; dst=Wcat+(size_t)4352*2048; n=4194304; break;
    case 3: src=wo; dst=wob;                    n=4194304; break;
    default:
      if (bx < 64)      { src=waq; dst=Wcat+(size_t)2048*2048; n=65536; }
      else if (bx < 128){ src=wak; dst=Wcat+(size_t)2080*2048; n=65536; bx-=64; }
      else if (bx < 512){ // zero pad rows 4160..4351 (192 rows = 393216 shorts)
        int idx = ((bx-128)*256 + threadIdx.x)*4;
        if (idx < 393216){
          short4v z = {0,0,0,0};
          *(short4v*)(Wcat + (size_t)4160*2048 + idx) = z;
        }
        return;
      } else return;
  }
  int idx = (bx*256 + threadIdx.x)*4;
  if (idx >= n) return;
  floatx4 v = *(const floatx4*)(src + idx);
  short4v o;
  o[0]=f2bf(v[0]); o[1]=f2bf(v[1]); o[2]=f2bf(v[2]); o[3]=f2bf(v[3]);
  *(short4v*)(dst + idx) = o;
}

// ------------- fused QKV GEMM: C = X @ Wcat^T, 256x256 tile, pipelined 4-phase ----
// R3 schedule (best measured: 130.4 us). Merged back to one 400-block launch
// (the R8 split was diagnostic only; flash_k's counters are now known).
__global__ __launch_bounds__(512,2)
void gemm_qkv(const short* __restrict__ A, const short* __restrict__ B,
              short* __restrict__ Cout, short* __restrict__ Vt, int bofs){
  __shared__ short SH[65536];   // 128 KiB
  const int K = 2048;
  int tid = threadIdx.x;
  int wave = tid>>6, lane = tid&63, quad = lane>>4, l16 = lane&15;
  int wm_i = wave>>2, wn_i = wave&3;

  int bid = blockIdx.x + bofs;
  int swz = (bid&7)*50 + (bid>>3);      // 8 XCDs x 50 blocks, bijective over 400
  int m0 = (swz & 15)*256;
  int n0 = (swz >> 4)*256;

  int srow = tid>>2;
  int sseg = (tid&3) ^ ((srow ^ (srow>>2)) & 3);
  const short* aS = A + (size_t)(m0 + srow)*K + sseg*8;
  const short* bS = B + (size_t)(n0 + srow)*K + sseg*8;
  int sdst = wave*512;                  // wave-uniform LDS base (shorts)

  int sx   = (l16 ^ (l16>>2)) & 3;
  int aoff = (wm_i*128 + l16)*32 + (quad^sx)*8;
  int boff = (wn_i*64  + l16)*32 + (quad^sx)*8;

  floatx4 acc[8][4] = {};
  short8v afA[8], afB[8], bfA[4], bfB[4];

#define QSTAGE(src, chunk) do{ \
    __builtin_amdgcn_global_load_lds(ASG(src), ASL(&SH[(chunk)+sdst]), 16, 0, 0); \
    __builtin_amdgcn_global_load_lds(ASG((src) + (size_t)128*2048), ASL(&SH[(chunk)+sdst+4096]), 16, 0, 0); \
  }while(0)
#define QBAR  asm volatile("s_barrier" ::: "memory")
#define QW4   asm volatile("s_waitcnt vmcnt(4)" ::: "memory")
#define MFMA_ __builtin_amdgcn_mfma_f32_16x16x32_bf16

  // prologue: stage tile0; validate A0/B0; preload P1 ops; stage A0 of tile1.
  QSTAGE(aS,            0);
  QSTAGE(bS,        32768);
  QSTAGE(aS+32,      8192);
  QSTAGE(bS+32, 32768+8192);
  QW4;              // A0_0, B0_0 landed (A1_0, B1_0 still in flight)
  QBAR;
  #pragma unroll
  for (int mf=0; mf<4; ++mf) afA[mf] = *(short8v*)&SH[0     + mf*512 + aoff];
  #pragma unroll
  for (int nf=0; nf<4; ++nf) bfA[nf] = *(short8v*)&SH[32768 + nf*512 + boff];
  QSTAGE(aS + 64, 16384);   // A0 of tile 1 -> buf1

  for (int t=0; t<32; ++t){
    int buf = t&1, nb = buf^1;
    int A0c = buf*16384,        A1c = A0c+8192;
    int B0c = 32768+buf*16384,  B1c = B0c+8192;
    int A0n = nb*16384,         A1n = A0n+8192;
    int B0n = 32768+nb*16384,   B1n = B0n+8192;
    int kn  = ((t+1)&31)*64;
    int kn2 = ((t+2)&31)*64;

    // P1: reads afA[4..7] (A0c, for P2); stage B0n; QW4 validates A1c,B1c; MFMA ks0 m0-3
    #pragma unroll
    for (int mf=4; mf<8; ++mf) afA[mf] = *(short8v*)&SH[A0c + mf*512 + aoff];
    QSTAGE(bS + kn, B0n);
    QW4;
    QBAR;
    __builtin_amdgcn_s_setprio(1);
    #pragma unroll
    for (int mf=0; mf<4; ++mf)
      #pragma unroll
      for (int nf=0; nf<4; ++nf)
        acc[mf][nf] = MFMA_(afA[mf], bfA[nf], acc[mf][nf], 0,0,0);
    __builtin_amdgcn_s_setprio(0);

    // P2: reads afB[0..3] (A1c) + bfB[0..3] (B1c); stage A1n; MFMA ks0 m4-7
    #pragma unroll
    for (int mf=0; mf<4; ++mf) afB[mf] = *(short8v*)&SH[A1c + mf*512 + aoff];
    #pragma unroll
    for (int nf=0; nf<4; ++nf) bfB[nf] = *(short8v*)&SH[B1c + nf*512 + boff];
    QSTAGE(aS + kn + 32, A1n);
    QBAR;
    __builtin_amdgcn_s_setprio(1);
    #pragma unroll
    for (int mf=4; mf<8; ++mf)
      #pragma unroll
      for (int nf=0; nf<4; ++nf)
        acc[mf][nf] = MFMA_(afA[mf], bfA[nf], acc[mf][nf], 0,0,0);
    __builtin_amdgcn_s_setprio(0);

    // P3: reads afB[4..7] (A1c); stage B1n; QW4 validates A0n,B0n; MFMA ks1 m0-3
    #pragma unroll
    for (int mf=4; mf<8; ++mf) afB[mf] = *(short8v*)&SH[A1c + mf*512 + aoff];
    QSTAGE(bS + kn + 32, B1n);
    QW4;
    QBAR;
    __builtin_amdgcn_s_setprio(1);
    #pragma unroll
    for (int mf=0; mf<4; ++mf)
      #pragma unroll
      for (int nf=0; nf<4; ++nf)
        acc[mf][nf] = MFMA_(afB[mf], bfB[nf], acc[mf][nf], 0,0,0);
    __builtin_amdgcn_s_setprio(0);

    // P0: reads afA[0..3] + bfA[0..3] from NEXT tile's A0/B0; stage A0(t+2); MFMA ks1 m4-7
    #pragma unroll
    for (int mf=0; mf<4; ++mf) afA[mf] = *(short8v*)&SH[A0n + mf*512 + aoff];
    #pragma unroll
    for (int nf=0; nf<4; ++nf) bfA[nf] = *(short8v*)&SH[B0n + nf*512 + boff];
    QSTAGE(aS + kn2, A0c);
    QBAR;
    __builtin_amdgcn_s_setprio(1);
    #pragma unroll
    for (int mf=4; mf<8; ++mf)
      #pragma unroll
      for (int nf=0; nf<4; ++nf)
        acc[mf][nf] = MFMA_(afB[mf], bfB[nf], acc[mf][nf], 0,0,0);
    __builtin_amdgcn_s_setprio(0);
  }

  __syncthreads();   // full drain: wrapped stages land before LDS reuse

  if (n0 < VOFF_){
    #pragma unroll
    for (int mf=0; mf<8; ++mf)
      #pragma unroll
      for (int r=0; r<4; ++r){
        size_t gm = (size_t)(m0 + wm_i*128 + mf*16 + quad*4 + r);
        #pragma unroll
        for (int nf=0; nf<4; ++nf)
          Cout[gm*NW_ + n0 + wn_i*64 + nf*16 + l16] = f2bf(acc[mf][nf][r]);
      }
  } else {
    // V tiles: 256x256 transpose through LDS, Vt[feat][token]
    short* T = SH;
    #pragma unroll
    for (int mf=0; mf<8; ++mf){
      int mb = wm_i*128 + mf*16 + quad*4;
      int mc = mb>>3, mi = mb&7;
      #pragma unroll
      for (int nf=0; nf<4; ++nf){
        int n = wn_i*64 + nf*16 + l16;
        short4v p;
        p[0]=f2bf(acc[mf][nf][0]); p[1]=f2bf(acc[mf][nf][1]);
        p[2]=f2bf(acc[mf][nf][2]); p[3]=f2bf(acc[mf][nf][3]);
        *(short4v*)&T[n*256 + ((mc ^ (n&31))*8) + mi] = p;
      }
    }
    __syncthreads();
    int f = tid>>1, half = tid&1;
    size_t vbase = (size_t)(n0 - VOFF_ + f)*4096 + m0;
    #pragma unroll
    for (int c=0; c<16; ++c){
      int cc = half*16 + c;
      short8v v = *(short8v*)&T[f*256 + ((cc ^ (f&31))*8)];
      *(short8v*)&Vt[vbase + cc*8] = v;
    }
  }
#undef QSTAGE
#undef QBAR
#undef QW4
#undef MFMA_
}

// ------------- O GEMM (m97-style, 128x128) -------------
__global__ __launch_bounds__(256,4)
void gemm_nt_f32(const short* __restrict__ A, const short* __restrict__ B,
                 float* __restrict__ Cout, int M, int N, int K){
  __shared__ short As[128][64];
  __shared__ short Bs[128][64];
  int tid = threadIdx.x;
  int wave = tid>>6, lane = tid&63, quad = lane>>4, l16 = lane&15;
  int l7 = l16&7;
  int m0 = blockIdx.x*128, n0 = blockIdx.y*128;
  int wm = (wave>>1)*64, wn = (wave&1)*64;
  floatx4 acc[4][4] = {};

  int lr = lane>>3;
  int sw = (lane&7) ^ lr;
  const short* Abase = A + (size_t)(m0 + wave*32 + lr)*K + sw*8;
  const short* Bbase = B + (size_t)(n0 + wave*32 + lr)*K + sw*8;

  for (int k0 = 0; k0 < K; k0 += 64){
    __syncthreads();
    #pragma unroll
    for (int i=0;i<4;i++){
      __builtin_amdgcn_global_load_lds(ASG(Abase + (size_t)(i*8)*K + k0),
                                       ASL(&As[wave*32 + i*8][0]), 16, 0, 0);
      __builtin_amdgcn_global_load_lds(ASG(Bbase + (size_t)(i*8)*K + k0),
                                       ASL(&Bs[wave*32 + i*8][0]), 16, 0, 0);
    }
    __syncthreads();
    #pragma unroll
    for (int ks=0; ks<2; ks++){
      short8v af[4], bf[4];
      #pragma unroll
      for (int i=0;i<4;i++) af[i] = *(short8v*)&As[wm + i*16 + l16][((ks*4+quad)^l7)*8];
      #pragma unroll
      for (int j=0;j<4;j++) bf[j] = *(short8v*)&Bs[wn + j*16 + l16][((ks*4+quad)^l7)*8];
      #pragma unroll
      for (int i=0;i<4;i++)
        #pragma unroll
        for (int j=0;j<4;j++)
          acc[i][j] = __builtin_amdgcn_mfma_f32_16x16x32_bf16(af[i], bf[j], acc[i][j], 0,0,0);
    }
  }
  #pragma unroll
  for (int i=0;i<4;i++)
    #pragma unroll
    for (int r=0;r<4;r++){
      int gm = m0 + wm + i*16 + quad*4 + r;
      #pragma unroll
      for (int j=0;j<4;j++){
        int gn = n0 + wn + j*16 + l16;
        Cout[(size_t)gm*N + gn] = acc[i][j][r];
      }
    }
}

// ---------------- RoPE on K (2 pairs/thread, 8B coalesced) ------------------
__global__ __launch_bounds__(256) void rope_k(short* __restrict__ X,
                                              const float* __restrict__ fcos,
                                              const float* __restrict__ fsin){
  int i = blockIdx.x*256 + threadIdx.x;   // 2,097,152 threads
  int row = i >> 9;                        // 4096 rows
  int p0  = (i & 511)*2;                   // pair index (even), handles p0 and p0+1
  int s = row & (S_-1);
  int pp = p0 & 63;                        // p0 even -> pp<=62, pp+1 never wraps
  float c0 = fcos[s*64+pp],   sn0 = fsin[s*64+pp];
  float c1 = fcos[s*64+pp+1], sn1 = fsin[s*64+pp+1];
  size_t a = (size_t)row*NW_ + 2112 + p0*2;
  int2v v = *(int2v*)(X + a);
  float re0 = bf2f((short)(v[0] & 0xffff)), im0 = bf2f((short)(v[0] >> 16));
  float re1 = bf2f((short)(v[1] & 0xffff)), im1 = bf2f((short)(v[1] >> 16));
  int2v o;
  o[0] = ((int)(unsigned short)f2bf(re0*sn0 + im0*c0) << 16) | (unsigned short)f2bf(re0*c0 - im0*sn0);
  o[1] = ((int)(unsigned short)f2bf(re1*sn1 + im1*c1) << 16) | (unsigned short)f2bf(re1*c1 - im1*sn1);
  *(int2v*)(X + a) = o;
}

// ---------------- gate precompute: G[b][kt][q][l16*4+j] = sigmoid(qh.kh) ----
__global__ __launch_bounds__(256)
void gate_k(const short* __restrict__ X, short* __restrict__ G){
  int kt = blockIdx.x, qt = blockIdx.y, b = blockIdx.z;
  if (kt > qt) return;
  int tid = threadIdx.x, wave = tid>>6, lane = tid&63, quad = lane>>4, l16 = lane&15;
  const float NL2E = -1.44269504f;

  short8v qh = *(const short8v*)&X[(size_t)(b*2048 + qt*64 + wave*16 + l16)*NW_ + 2048 + quad*8];
  floatx4 am[4];
  #pragma unroll
  for (int j=0;j<4;j++){
    short8v kh = *(const short8v*)&X[(size_t)(b*2048 + kt*64 + j*16 + l16)*NW_ + 2080 + quad*8];
    floatx4 z = {0.f,0.f,0.f,0.f};
    am[j] = __builtin_amdgcn_mfma_f32_16x16x32_bf16(qh, kh, z, 0,0,0);
  }
  short* Gd = G + (((size_t)(b*32 + kt)*2048) + qt*64 + wave*16 + quad*4)*64 + l16*4;
  #pragma unroll
  for (int r=0;r<4;r++){
    short4v sv;
    #pragma unroll
    for (int j=0;j<4;j++){
      float g = __builtin_amdgcn_rcpf(1.f + __builtin_amdgcn_exp2f(am[j][r]*NL2E));
      sv[j] = f2bf(g);
    }
    *(short4v*)(Gd + (size_t)r*64) = sv;
  }
}

// ---------------- Flash attention v6: 1024 blocks, 3 blocks/CU, longest-first
// R8 counters: flash = 82us with ALL pipes <35% (MfmaUtil 17.6, VALUBusy 33.6,
// HBM 13.7%) and Occupancy 19.4% -> latency-bound serial chain with ~1.5 waves/
// SIMD. Fix = TLP (Guideline 1): un-pair q-tiles (one qt per block, 1024 blocks),
// longest strips first (qt = 31-by so qt=31 launches earliest), launch_bounds
// (256,3): 41984B LDS x3 = 123KB -> 3 blocks/CU = 12 waves/CU (1.5x R8).
// XCD locality preserved: linear id %8 = h%8. Strip-loop body unchanged.
__global__ __launch_bounds__(256,3)
void flash_k(const short* __restrict__ Qc, const short* __restrict__ Vt,
             const short* __restrict__ G, const float* __restrict__ fcos,
             const float* __restrict__ fsin, short* __restrict__ O){
  int h = blockIdx.x, b = blockIdx.z;
  int qt = 31 - blockIdx.y;          // longest-first
  int tid = threadIdx.x, wave = tid>>6, lane = tid&63, quad = lane>>4, l16 = lane&15;
  int l7 = l16&7;

  __shared__ short Ks [64][128];     // 16 KB
  __shared__ short Vts[128][64];     // 16 KB
  __shared__ short Ps [4][16][72];   // 9 KB   (41984 B total)

  const float CS = 1.44269504f * 0.08838834764831845f;  // log2(e)/sqrt(128)

  int srow = qt*64 + wave*16 + l16;
  size_t qrow = (size_t)(b*2048 + srow);
  short8v qf[4];
  #pragma unroll
  for (int ks=0;ks<4;ks++)
    qf[ks] = *(const short8v*)&Qc[qrow*NW_ + h*128 + ks*32 + quad*8];
  // fused RoPE on Q fragments (pairs are lane-local)
  #pragma unroll
  for (int ks=0;ks<4;ks++)
    #pragma unroll
    for (int jj=0;jj<4;jj++){
      float re = bf2f(qf[ks][2*jj]), im = bf2f(qf[ks][2*jj+1]);
      int p = ks*16 + quad*4 + jj;
      float c = fcos[srow*64 + p], sn = fsin[srow*64 + p];
      qf[ks][2*jj]   = f2bf(re*c - im*sn);
      qf[ks][2*jj+1] = f2bf(re*sn + im*c);
    }

  floatx4 oacc[8] = {};
  float lp[4] = {0.f,0.f,0.f,0.f};

  for (int kt=0; kt<=qt; kt++){
    int k0 = kt*64;
    __syncthreads();   // previous strip's LDS readers done
    {
      const short* Ksrc = Qc + ((size_t)(b*2048 + k0 + wave*16))*NW_ + 2112 + h*128;
      int r4 = lane>>4, c16 = lane&15;
      #pragma unroll
      for (int j=0;j<4;j++)
        __builtin_amdgcn_global_load_lds(
          ASG(Ksrc + (size_t)(j*4 + r4)*NW_ + ((c16 ^ r4 ^ ((j&1)*4))*8)),
          ASL(&Ks[wave*16 + j*4][0]), 16, 0, 0);
      const short* Vsrc = Vt + ((size_t)(h*128 + wave*32 + (lane>>3)))*4096 + b*2048 + k0
                          + (((lane&7) ^ (lane>>3))*8);
      #pragma unroll
      for (int j=0;j<4;j++)
        __builtin_amdgcn_global_load_lds(
          ASG(Vsrc + (size_t)(j*8)*4096),
          ASL(&Vts[wave*32 + j*8][0]), 16, 0, 0);
    }
    __syncthreads();   // staging complete (implicit vmcnt(0) drain)

    const short* gb = G + (((size_t)(b*32 + kt)*2048) + qt*64 + wave*16 + quad*4)*64 + l16*4;
    short4v g4[4];
    #pragma unroll
    for (int r=0;r<4;r++) g4[r] = *(const short4v*)(gb + (size_t)r*64);

    // ---- QK^T ----
    floatx4 sacc[4] = {};
    #pragma unroll
    for (int j=0;j<4;j++)
      #pragma unroll
      for (int ks2=0;ks2<4;ks2++){
        short8v kf = *(short8v*)&Ks[j*16+l16][((ks2*4+quad)^l7)*8];
        sacc[j] = __builtin_amdgcn_mfma_f32_16x16x32_bf16(qf[ks2], kf, sacc[j], 0,0,0);
      }

    // ---- mask + exp + gate -> Ps ----
    bool diag = (kt == qt);
    int qbase = wave*16 + quad*4;
    #pragma unroll
    for (int j=0;j<4;j++){
      int kin = j*16 + l16;
      #pragma unroll
      for (int r=0;r<4;r++){
        bool keep = !diag || (kin <= qbase + r);
        float p = keep ? __builtin_amdgcn_exp2f(sacc[j][r]*CS) : 0.f;
        lp[r] += p;
        Ps[wave][quad*4+r][j*16+l16] = f2bf(p * bf2f(g4[r][j]));
      }
    }

    // ---- P·V ----
    #pragma unroll
    for (int ks2=0; ks2<2; ks2++){
      short8v pf = *(short8v*)&Ps[wave][l16][ks2*32 + quad*8];
      #pragma unroll
      for (int dt=0; dt<8; dt++){
        short8v vf = *(short8v*)&Vts[dt*16 + l16][((ks2*4+quad)^l7)*8];
        oacc[dt] = __builtin_amdgcn_mfma_f32_16x16x32_bf16(pf, vf, oacc[dt], 0,0,0);
      }
    }
  }

  #pragma unroll
  for (int r=0;r<4;r++)
    #pragma unroll
    for (int off=1; off<16; off<<=1)
      lp[r] += __shfl_xor(lp[r], off, 64);
  #pragma unroll
  for (int r=0;r<4;r++){
    float inv = __builtin_amdgcn_rcpf(lp[r]);
    size_t orow = (size_t)(b*2048 + qt*64 + wave*16 + quad*4 + r);
    #pragma unroll
    for (int dt=0;dt<8;dt++)
      O[orow*2048 + h*128 + dt*16 + l16] = f2bf(oacc[dt][r]*inv);
  }
}

// ---------------- launch ----------------
extern "C" void kernel_launch(void* const* d_in, const int* in_sizes, int n_in,
                              void* d_out, int out_size, void* d_ws, size_t ws_size,
                              hipStream_t stream){
  const float* x    = (const float*)d_in[0];
  const float* fcos = (const float*)d_in[2];
  const float* fsin = (const float*)d_in[3];
  const float* wq   = (const float*)d_in[4];
  const float* wk   = (const float*)d_in[5];
  const float* wv   = (const float*)d_in[6];
  const float* wo   = (const float*)d_in[7];
  const float* waq  = (const float*)d_in[8];
  const float* wak  = (const float*)d_in[9];
  float* out = (float*)d_out;

  char* ws = (char*)d_ws;
  size_t off = 0;
  short* xb   = (short*)(ws + off); off += (size_t)4096*2048*2;   // x bf16; later G (gate)
  short* Wcat = (short*)(ws + off); off += (size_t)NW_*2048*2;    // fused weights; later O
  short* wob  = (short*)(ws + off); off += (size_t)2048*2048*2;
  short* XQKV = (short*)(ws + off); off += (size_t)4096*NW_*2;    // [Q|qh|kh|K|pad|(V unused)]
  short* Vtb  = (short*)(ws + off); off += (size_t)2048*4096*2;   // V transposed
  short* G    = xb;    // gate overlays xb (x dead after gemm_qkv)
  short* Ob   = Wcat;  // flash output overlays Wcat (dead after gemm_qkv)

  cvt_k<<<8192,256,0,stream>>>(x, xb, 8388608);
  cvt_w<<<dim3(4096,5),256,0,stream>>>(wq, waq, wak, wk, wv, wo, Wcat, wob);

  gemm_qkv<<<dim3(400),512,0,stream>>>(xb, Wcat, XQKV, Vtb, 0);

  rope_k<<<8192,256,0,stream>>>(XQKV, fcos, fsin);
  gate_k<<<dim3(32,32,2),256,0,stream>>>(XQKV, G);

  flash_k<<<dim3(16,32,2),256,0,stream>>>(XQKV, Vtb, G, fcos, fsin, Ob);

  gemm_nt_f32<<<dim3(32,16),256,0,stream>>>(Ob, wob, out, 4096, 2048, 2048);
}

// Round 11
// 412.752 us; speedup vs baseline: 1.0201x; 1.0201x over previous
//
#include <hip/hip_runtime.h>

typedef __attribute__((ext_vector_type(8))) short short8v;
typedef __attribute__((ext_vector_type(4))) short short4v;
typedef __attribute__((ext_vector_type(4))) float floatx4;
typedef __attribute__((ext_vector_type(2))) int int2v;

#define S_    2048
#define DIM_  2048
#define NW_   6400   // wq 0..2047 | waq 2048..2079 | wak 2080..2111 | wk 2112..4159 | pad 4160..4351 | wv 4352..6399
#define VOFF_ 4352

#define ASG(p) ((__attribute__((address_space(1))) void*)(p))
#define ASL(p) ((__attribute__((address_space(3))) void*)(p))

__device__ __forceinline__ short f2bf(float f){
  union { float f; unsigned u; } c; c.f = f;
  unsigned u = c.u;
  unsigned r = (u + 0x7fffu + ((u >> 16) & 1u)) >> 16;
  return (short)r;
}
__device__ __forceinline__ float bf2f(short s){
  union { unsigned u; float f; } c; c.u = ((unsigned)(unsigned short)s) << 16;
  return c.f;
}

// ---------------- fused f32->bf16 conversion: x + all weights, ONE launch ----
// 1D grid 25088: [0,8192) x | [ ,12288) wq | [ ,16384) wk | [ ,20480) wv |
// [ ,24576) wo | [ ,24640) waq | [ ,24704) wak | [ ,25088) zero-pad (384)
__global__ __launch_bounds__(256)
void cvt_all(const float* __restrict__ x,  const float* __restrict__ wq,
             const float* __restrict__ wk, const float* __restrict__ wv,
             const float* __restrict__ wo, const float* __restrict__ waq,
             const float* __restrict__ wak,
             short* __restrict__ xb, short* __restrict__ Wcat,
             short* __restrict__ wob){
  int bid = blockIdx.x;
  const float* src; short* dst; int n, bx;
  if      (bid <  8192){ src=x;   dst=xb;                         n=8388608; bx=bid; }
  else if (bid < 12288){ src=wq;  dst=Wcat;                       n=4194304; bx=bid-8192; }
  else if (bid < 16384){ src=wk;  dst=Wcat+(size_t)2112*2048;     n=4194304; bx=bid-12288; }
  else if (bid < 20480){ src=wv;  dst=Wcat+(size_t)4352*2048;     n=4194304; bx=bid-16384; }
  else if (bid < 24576){ src=wo;  dst=wob;                        n=4194304; bx=bid-20480; }
  else if (bid < 24640){ src=waq; dst=Wcat+(size_t)2048*2048;     n=65536;   bx=bid-24576; }
  else if (bid < 24704){ src=wak; dst=Wcat+(size_t)2080*2048;     n=65536;   bx=bid-24640; }
  else { // zero pad rows 4160..4351: 384 blocks x 1024 shorts = 393216 exact
    int idx = ((bid-24704)*256 + threadIdx.x)*4;
    short4v z = {0,0,0,0};
    *(short4v*)(Wcat + (size_t)4160*2048 + idx) = z;
    return;
  }
  int idx = (bx*256 + threadIdx.x)*4;
  if (idx >= n) return;
  floatx4 v = *(const floatx4*)(src + idx);
  short4v o;
  o[0]=f2bf(v[0]); o[1]=f2bf(v[1]); o[2]=f2bf(v[2]); o[3]=f2bf(v[3]);
  *(short4v*)(dst + idx) = o;
}

// ------------- fused QKV GEMM: C = X @ Wcat^T, 256x256 tile, pipelined 4-phase ----
// R3 schedule (best measured: ~129-130 us), single 400-block launch.
__global__ __launch_bounds__(512,2)
void gemm_qkv(const short* __restrict__ A, const short* __restrict__ B,
              short* __restrict__ Cout, short* __restrict__ Vt){
  __shared__ short SH[65536];   // 128 KiB
  const int K = 2048;
  int tid = threadIdx.x;
  int wave = tid>>6, lane = tid&63, quad = lane>>4, l16 = lane&15;
  int wm_i = wave>>2, wn_i = wave&3;

  int bid = blockIdx.x;
  int swz = (bid&7)*50 + (bid>>3);      // 8 XCDs x 50 blocks, bijective over 400
  int m0 = (swz & 15)*256;
  int n0 = (swz >> 4)*256;

  int srow = tid>>2;
  int sseg = (tid&3) ^ ((srow ^ (srow>>2)) & 3);
  const short* aS = A + (size_t)(m0 + srow)*K + sseg*8;
  const short* bS = B + (size_t)(n0 + srow)*K + sseg*8;
  int sdst = wave*512;

  int sx   = (l16 ^ (l16>>2)) & 3;
  int aoff = (wm_i*128 + l16)*32 + (quad^sx)*8;
  int boff = (wn_i*64  + l16)*32 + (quad^sx)*8;

  floatx4 acc[8][4] = {};
  short8v afA[8], afB[8], bfA[4], bfB[4];

#define QSTAGE(src, chunk) do{ \
    __builtin_amdgcn_global_load_lds(ASG(src), ASL(&SH[(chunk)+sdst]), 16, 0, 0); \
    __builtin_amdgcn_global_load_lds(ASG((src) + (size_t)128*2048), ASL(&SH[(chunk)+sdst+4096]), 16, 0, 0); \
  }while(0)
#define QBAR  asm volatile("s_barrier" ::: "memory")
#define QW4   asm volatile("s_waitcnt vmcnt(4)" ::: "memory")
#define MFMA_ __builtin_amdgcn_mfma_f32_16x16x32_bf16

  QSTAGE(aS,            0);
  QSTAGE(bS,        32768);
  QSTAGE(aS+32,      8192);
  QSTAGE(bS+32, 32768+8192);
  QW4;
  QBAR;
  #pragma unroll
  for (int mf=0; mf<4; ++mf) afA[mf] = *(short8v*)&SH[0     + mf*512 + aoff];
  #pragma unroll
  for (int nf=0; nf<4; ++nf) bfA[nf] = *(short8v*)&SH[32768 + nf*512 + boff];
  QSTAGE(aS + 64, 16384);   // A0 of tile 1 -> buf1

  for (int t=0; t<32; ++t){
    int buf = t&1, nb = buf^1;
    int A0c = buf*16384,        A1c = A0c+8192;
    int B0c = 32768+buf*16384,  B1c = B0c+8192;
    int A0n = nb*16384,         A1n = A0n+8192;
    int B0n = 32768+nb*16384,   B1n = B0n+8192;
    int kn  = ((t+1)&31)*64;
    int kn2 = ((t+2)&31)*64;

    // P1
    #pragma unroll
    for (int mf=4; mf<8; ++mf) afA[mf] = *(short8v*)&SH[A0c + mf*512 + aoff];
    QSTAGE(bS + kn, B0n);
    QW4;
    QBAR;
    __builtin_amdgcn_s_setprio(1);
    #pragma unroll
    for (int mf=0; mf<4; ++mf)
      #pragma unroll
      for (int nf=0; nf<4; ++nf)
        acc[mf][nf] = MFMA_(afA[mf], bfA[nf], acc[mf][nf], 0,0,0);
    __builtin_amdgcn_s_setprio(0);

    // P2
    #pragma unroll
    for (int mf=0; mf<4; ++mf) afB[mf] = *(short8v*)&SH[A1c + mf*512 + aoff];
    #pragma unroll
    for (int nf=0; nf<4; ++nf) bfB[nf] = *(short8v*)&SH[B1c + nf*512 + boff];
    QSTAGE(aS + kn + 32, A1n);
    QBAR;
    __builtin_amdgcn_s_setprio(1);
    #pragma unroll
    for (int mf=4; mf<8; ++mf)
      #pragma unroll
      for (int nf=0; nf<4; ++nf)
        acc[mf][nf] = MFMA_(afA[mf], bfA[nf], acc[mf][nf], 0,0,0);
    __builtin_amdgcn_s_setprio(0);

    // P3
    #pragma unroll
    for (int mf=4; mf<8; ++mf) afB[mf] = *(short8v*)&SH[A1c + mf*512 + aoff];
    QSTAGE(bS + kn + 32, B1n);
    QW4;
    QBAR;
    __builtin_amdgcn_s_setprio(1);
    #pragma unroll
    for (int mf=0; mf<4; ++mf)
      #pragma unroll
      for (int nf=0; nf<4; ++nf)
        acc[mf][nf] = MFMA_(afB[mf], bfB[nf], acc[mf][nf], 0,0,0);
    __builtin_amdgcn_s_setprio(0);

    // P0
    #pragma unroll
    for (int mf=0; mf<4; ++mf) afA[mf] = *(short8v*)&SH[A0n + mf*512 + aoff];
    #pragma unroll
    for (int nf=0; nf<4; ++nf) bfA[nf] = *(short8v*)&SH[B0n + nf*512 + boff];
    QSTAGE(aS + kn2, A0c);
    QBAR;
    __builtin_amdgcn_s_setprio(1);
    #pragma unroll
    for (int mf=4; mf<8; ++mf)
      #pragma unroll
      for (int nf=0; nf<4; ++nf)
        acc[mf][nf] = MFMA_(afB[mf], bfB[nf], acc[mf][nf], 0,0,0);
    __builtin_amdgcn_s_setprio(0);
  }

  __syncthreads();

  if (n0 < VOFF_){
    #pragma unroll
    for (int mf=0; mf<8; ++mf)
      #pragma unroll
      for (int r=0; r<4; ++r){
        size_t gm = (size_t)(m0 + wm_i*128 + mf*16 + quad*4 + r);
        #pragma unroll
        for (int nf=0; nf<4; ++nf)
          Cout[gm*NW_ + n0 + wn_i*64 + nf*16 + l16] = f2bf(acc[mf][nf][r]);
      }
  } else {
    short* T = SH;
    #pragma unroll
    for (int mf=0; mf<8; ++mf){
      int mb = wm_i*128 + mf*16 + quad*4;
      int mc = mb>>3, mi = mb&7;
      #pragma unroll
      for (int nf=0; nf<4; ++nf){
        int n = wn_i*64 + nf*16 + l16;
        short4v p;
        p[0]=f2bf(acc[mf][nf][0]); p[1]=f2bf(acc[mf][nf][1]);
        p[2]=f2bf(acc[mf][nf][2]); p[3]=f2bf(acc[mf][nf][3]);
        *(short4v*)&T[n*256 + ((mc ^ (n&31))*8) + mi] = p;
      }
    }
    __syncthreads();
    int f = tid>>1, half = tid&1;
    size_t vbase = (size_t)(n0 - VOFF_ + f)*4096 + m0;
    #pragma unroll
    for (int c=0; c<16; ++c){
      int cc = half*16 + c;
      short8v v = *(short8v*)&T[f*256 + ((cc ^ (f&31))*8)];
      *(short8v*)&Vt[vbase + cc*8] = v;
    }
  }
#undef QSTAGE
#undef QBAR
#undef QW4
#undef MFMA_
}

// ------------- O GEMM (m97-style, 128x128) -------------
__global__ __launch_bounds__(256,4)
void gemm_nt_f32(const short* __restrict__ A, const short* __restrict__ B,
                 float* __restrict__ Cout, int M, int N, int K){
  __shared__ short As[128][64];
  __shared__ short Bs[128][64];
  int tid = threadIdx.x;
  int wave = tid>>6, lane = tid&63, quad = lane>>4, l16 = lane&15;
  int l7 = l16&7;
  int m0 = blockIdx.x*128, n0 = blockIdx.y*128;
  int wm = (wave>>1)*64, wn = (wave&1)*64;
  floatx4 acc[4][4] = {};

  int lr = lane>>3;
  int sw = (lane&7) ^ lr;
  const short* Abase = A + (size_t)(m0 + wave*32 + lr)*K + sw*8;
  const short* Bbase = B + (size_t)(n0 + wave*32 + lr)*K + sw*8;

  for (int k0 = 0; k0 < K; k0 += 64){
    __syncthreads();
    #pragma unroll
    for (int i=0;i<4;i++){
      __builtin_amdgcn_global_load_lds(ASG(Abase + (size_t)(i*8)*K + k0),
                                       ASL(&As[wave*32 + i*8][0]), 16, 0, 0);
      __builtin_amdgcn_global_load_lds(ASG(Bbase + (size_t)(i*8)*K + k0),
                                       ASL(&Bs[wave*32 + i*8][0]), 16, 0, 0);
    }
    __syncthreads();
    #pragma unroll
    for (int ks=0; ks<2; ks++){
      short8v af[4], bf[4];
      #pragma unroll
      for (int i=0;i<4;i++) af[i] = *(short8v*)&As[wm + i*16 + l16][((ks*4+quad)^l7)*8];
      #pragma unroll
      for (int j=0;j<4;j++) bf[j] = *(short8v*)&Bs[wn + j*16 + l16][((ks*4+quad)^l7)*8];
      #pragma unroll
      for (int i=0;i<4;i++)
        #pragma unroll
        for (int j=0;j<4;j++)
          acc[i][j] = __builtin_amdgcn_mfma_f32_16x16x32_bf16(af[i], bf[j], acc[i][j], 0,0,0);
    }
  }
  #pragma unroll
  for (int i=0;i<4;i++)
    #pragma unroll
    for (int r=0;r<4;r++){
      int gm = m0 + wm + i*16 + quad*4 + r;
      #pragma unroll
      for (int j=0;j<4;j++){
        int gn = n0 + wn + j*16 + l16;
        Cout[(size_t)gm*N + gn] = acc[i][j][r];
      }
    }
}

// ---------------- fused RoPE(K) + gate, ONE launch --------------------------
// 1D grid 10240: [0,8192) rope (2 pairs/thread, 8B coalesced); [8192,10240)
// gate: g=bid-8192 -> kt=g&31, qt=(g>>5)&31, b=g>>10 (kt>qt blocks exit).
// Independent regions: rope touches cols 2112+, gate reads cols 2048..2112.
__global__ __launch_bounds__(256)
void rope_gate(short* __restrict__ X, const float* __restrict__ fcos,
               const float* __restrict__ fsin, short* __restrict__ G){
  int bid = blockIdx.x;
  if (bid < 8192){
    int i = bid*256 + threadIdx.x;
    int row = i >> 9;
    int p0  = (i & 511)*2;
    int s = row & (S_-1);
    int pp = p0 & 63;
    float c0 = fcos[s*64+pp],   sn0 = fsin[s*64+pp];
    float c1 = fcos[s*64+pp+1], sn1 = fsin[s*64+pp+1];
    size_t a = (size_t)row*NW_ + 2112 + p0*2;
    int2v v = *(int2v*)(X + a);
    float re0 = bf2f((short)(v[0] & 0xffff)), im0 = bf2f((short)(v[0] >> 16));
    float re1 = bf2f((short)(v[1] & 0xffff)), im1 = bf2f((short)(v[1] >> 16));
    int2v o;
    o[0] = ((int)(unsigned short)f2bf(re0*sn0 + im0*c0) << 16) | (unsigned short)f2bf(re0*c0 - im0*sn0);
    o[1] = ((int)(unsigned short)f2bf(re1*sn1 + im1*c1) << 16) | (unsigned short)f2bf(re1*c1 - im1*sn1);
    *(int2v*)(X + a) = o;
    return;
  }
  int g = bid - 8192;
  int kt = g & 31, qt = (g>>5)&31, b = g>>10;
  if (kt > qt) return;
  int tid = threadIdx.x, wave = tid>>6, lane = tid&63, quad = lane>>4, l16 = lane&15;
  const float NL2E = -1.44269504f;

  short8v qh = *(const short8v*)&X[(size_t)(b*2048 + qt*64 + wave*16 + l16)*NW_ + 2048 + quad*8];
  floatx4 am[4];
  #pragma unroll
  for (int j=0;j<4;j++){
    short8v kh = *(const short8v*)&X[(size_t)(b*2048 + kt*64 + j*16 + l16)*NW_ + 2080 + quad*8];
    floatx4 z = {0.f,0.f,0.f,0.f};
    am[j] = __builtin_amdgcn_mfma_f32_16x16x32_bf16(qh, kh, z, 0,0,0);
  }
  short* Gd = G + (((size_t)(b*32 + kt)*2048) + qt*64 + wave*16 + quad*4)*64 + l16*4;
  #pragma unroll
  for (int r=0;r<4;r++){
    short4v sv;
    #pragma unroll
    for (int j=0;j<4;j++){
      float gg = __builtin_amdgcn_rcpf(1.f + __builtin_amdgcn_exp2f(am[j][r]*NL2E));
      sv[j] = f2bf(gg);
    }
    *(short4v*)(Gd + (size_t)r*64) = sv;
  }
}

// ---------------- Flash attention v7: paired (measured-best) + cvt_pk -------
// R9 falsified the TLP theory (3 blocks/CU cost +14us: co-resident blocks share
// no K/V -> cache thrash). Revert to v4 paired (256,2) = measured 82us; cut the
// VALU term (33.6% busy) with v_cvt_pk_bf16_f32: 16 manual f2bf (48 VALU ops)
// -> 8 cvt_pk + 8 extracts in the P-store path. Addresses byte-identical.
__global__ __launch_bounds__(256,2)
void flash_k(const short* __restrict__ Qc, const short* __restrict__ Vt,
             const short* __restrict__ G, const float* __restrict__ fcos,
             const float* __restrict__ fsin, short* __restrict__ O){
  int h = blockIdx.x, pi = blockIdx.y, b = blockIdx.z;
  int tid = threadIdx.x, wave = tid>>6, lane = tid&63, quad = lane>>4, l16 = lane&15;
  int l7 = l16&7;

  __shared__ short Ks [64][128];     // 16 KB
  __shared__ short Vts[128][64];     // 16 KB
  __shared__ short Ps [4][16][72];   // 9 KB

  const float CS = 1.44269504f * 0.08838834764831845f;  // log2(e)/sqrt(128)

  for (int ph = 0; ph < 2; ph++){
    int qt = ph ? pi : 31 - pi;
    int srow = qt*64 + wave*16 + l16;
    size_t qrow = (size_t)(b*2048 + srow);
    short8v qf[4];
    #pragma unroll
    for (int ks=0;ks<4;ks++)
      qf[ks] = *(const short8v*)&Qc[qrow*NW_ + h*128 + ks*32 + quad*8];
    #pragma unroll
    for (int ks=0;ks<4;ks++)
      #pragma unroll
      for (int jj=0;jj<4;jj++){
        float re = bf2f(qf[ks][2*jj]), im = bf2f(qf[ks][2*jj+1]);
        int p = ks*16 + quad*4 + jj;
        float c = fcos[srow*64 + p], sn = fsin[srow*64 + p];
        qf[ks][2*jj]   = f2bf(re*c - im*sn);
        qf[ks][2*jj+1] = f2bf(re*sn + im*c);
      }

    floatx4 oacc[8] = {};
    float lp[4] = {0.f,0.f,0.f,0.f};

    for (int kt=0; kt<=qt; kt++){
      int k0 = kt*64;
      __syncthreads();
      {
        const short* Ksrc = Qc + ((size_t)(b*2048 + k0 + wave*16))*NW_ + 2112 + h*128;
        int r4 = lane>>4, c16 = lane&15;
        #pragma unroll
        for (int j=0;j<4;j++)
          __builtin_amdgcn_global_load_lds(
            ASG(Ksrc + (size_t)(j*4 + r4)*NW_ + ((c16 ^ r4 ^ ((j&1)*4))*8)),
            ASL(&Ks[wave*16 + j*4][0]), 16, 0, 0);
        const short* Vsrc = Vt + ((size_t)(h*128 + wave*32 + (lane>>3)))*4096 + b*2048 + k0
                            + (((lane&7) ^ (lane>>3))*8);
        #pragma unroll
        for (int j=0;j<4;j++)
          __builtin_amdgcn_global_load_lds(
            ASG(Vsrc + (size_t)(j*8)*4096),
            ASL(&Vts[wave*32 + j*8][0]), 16, 0, 0);
      }
      __syncthreads();

      const short* gb = G + (((size_t)(b*32 + kt)*2048) + qt*64 + wave*16 + quad*4)*64 + l16*4;
      short4v g4[4];
      #pragma unroll
      for (int r=0;r<4;r++) g4[r] = *(const short4v*)(gb + (size_t)r*64);

      // ---- QK^T ----
      floatx4 sacc[4] = {};
      #pragma unroll
      for (int j=0;j<4;j++)
        #pragma unroll
        for (int ks2=0;ks2<4;ks2++){
          short8v kf = *(short8v*)&Ks[j*16+l16][((ks2*4+quad)^l7)*8];
          sacc[j] = __builtin_amdgcn_mfma_f32_16x16x32_bf16(qf[ks2], kf, sacc[j], 0,0,0);
        }

      // ---- mask + exp + gate (f32) ----
      bool diag = (kt == qt);
      int qbase = wave*16 + quad*4;
      float pv0[4], pv1[4], pv2[4], pv3[4];   // [j] per r, static-indexed
      #pragma unroll
      for (int r=0;r<4;r++){
        #pragma unroll
        for (int j=0;j<4;j++){
          int kin = j*16 + l16;
          bool keep = !diag || (kin <= qbase + r);
          float p = keep ? __builtin_amdgcn_exp2f(sacc[j][r]*CS) : 0.f;
          lp[r] += p;
          float g = p * bf2f(g4[r][j]);
          if (j==0) pv0[r]=g; else if (j==1) pv1[r]=g; else if (j==2) pv2[r]=g; else pv3[r]=g;
        }
      }
      // ---- pack to bf16 via v_cvt_pk (1 op per 2 values) -> Ps ----
      #pragma unroll
      for (int r=0;r<4;r++){
        unsigned u01, u23;
        asm("v_cvt_pk_bf16_f32 %0, %1, %2" : "=v"(u01) : "v"(pv0[r]), "v"(pv1[r]));
        asm("v_cvt_pk_bf16_f32 %0, %1, %2" : "=v"(u23) : "v"(pv2[r]), "v"(pv3[r]));
        short* Prow = &Ps[wave][quad*4+r][l16];
        Prow[ 0] = (short)(u01 & 0xffffu);
        Prow[16] = (short)(u01 >> 16);
        Prow[32] = (short)(u23 & 0xffffu);
        Prow[48] = (short)(u23 >> 16);
      }

      // ---- P·V ----
      #pragma unroll
      for (int ks2=0; ks2<2; ks2++){
        short8v pf = *(short8v*)&Ps[wave][l16][ks2*32 + quad*8];
        #pragma unroll
        for (int dt=0; dt<8; dt++){
          short8v vf = *(short8v*)&Vts[dt*16 + l16][((ks2*4+quad)^l7)*8];
          oacc[dt] = __builtin_amdgcn_mfma_f32_16x16x32_bf16(pf, vf, oacc[dt], 0,0,0);
        }
      }
    }

    #pragma unroll
    for (int r=0;r<4;r++)
      #pragma unroll
      for (int off=1; off<16; off<<=1)
        lp[r] += __shfl_xor(lp[r], off, 64);
    #pragma unroll
    for (int r=0;r<4;r++){
      float inv = __builtin_amdgcn_rcpf(lp[r]);
      size_t orow = (size_t)(b*2048 + qt*64 + wave*16 + quad*4 + r);
      #pragma unroll
      for (int dt=0;dt<8;dt++)
        O[orow*2048 + h*128 + dt*16 + l16] = f2bf(oacc[dt][r]*inv);
    }
  }
}

// ---------------- launch (5 dispatches, was 7) ----------------
extern "C" void kernel_launch(void* const* d_in, const int* in_sizes, int n_in,
                              void* d_out, int out_size, void* d_ws, size_t ws_size,
                              hipStream_t stream){
  const float* x    = (const float*)d_in[0];
  const float* fcos = (const float*)d_in[2];
  const float* fsin = (const float*)d_in[3];
  const float* wq   = (const float*)d_in[4];
  const float* wk   = (const float*)d_in[5];
  const float* wv   = (const float*)d_in[6];
  const float* wo   = (const float*)d_in[7];
  const float* waq  = (const float*)d_in[8];
  const float* wak  = (const float*)d_in[9];
  float* out = (float*)d_out;

  char* ws = (char*)d_ws;
  size_t off = 0;
  short* xb   = (short*)(ws + off); off += (size_t)4096*2048*2;   // x bf16; later G (gate)
  short* Wcat = (short*)(ws + off); off += (size_t)NW_*2048*2;    // fused weights; later O
  short* wob  = (short*)(ws + off); off += (size_t)2048*2048*2;
  short* XQKV = (short*)(ws + off); off += (size_t)4096*NW_*2;    // [Q|qh|kh|K|pad]
  short* Vtb  = (short*)(ws + off); off += (size_t)2048*4096*2;   // V transposed
  short* G    = xb;    // gate overlays xb (x dead after gemm_qkv)
  short* Ob   = Wcat;  // flash output overlays Wcat (dead after gemm_qkv)

  cvt_all<<<25088,256,0,stream>>>(x, wq, wk, wv, wo, waq, wak, xb, Wcat, wob);

  gemm_qkv<<<dim3(400),512,0,stream>>>(xb, Wcat, XQKV, Vtb);

  rope_gate<<<10240,256,0,stream>>>(XQKV, fcos, fsin, G);

  flash_k<<<dim3(16,16,2),256,0,stream>>>(XQKV, Vtb, G, fcos, fsin, Ob);

  gemm_nt_f32<<<dim3(32,16),256,0,stream>>>(Ob, wob, out, 4096, 2048, 2048);
}

// Round 12
// 406.880 us; speedup vs baseline: 1.0348x; 1.0144x over previous
//
#include <hip/hip_runtime.h>

typedef __attribute__((ext_vector_type(8))) short short8v;
typedef __attribute__((ext_vector_type(4))) short short4v;
typedef __attribute__((ext_vector_type(4))) float floatx4;
typedef __attribute__((ext_vector_type(2))) int int2v;

#define S_    2048
#define DIM_  2048
#define NW_   6400   // wq 0..2047 | waq 2048..2079 | wak 2080..2111 | wk 2112..4159 | pad 4160..4351 | wv 4352..6399
#define VOFF_ 4352

#define ASG(p) ((__attribute__((address_space(1))) void*)(p))
#define ASL(p) ((__attribute__((address_space(3))) void*)(p))

__device__ __forceinline__ short f2bf(float f){
  union { float f; unsigned u; } c; c.f = f;
  unsigned u = c.u;
  unsigned r = (u + 0x7fffu + ((u >> 16) & 1u)) >> 16;
  return (short)r;
}
__device__ __forceinline__ float bf2f(short s){
  union { unsigned u; float f; } c; c.u = ((unsigned)(unsigned short)s) << 16;
  return c.f;
}

// ---------------- fused f32->bf16 conversion: x + all weights, ONE launch ----
__global__ __launch_bounds__(256)
void cvt_all(const float* __restrict__ x,  const float* __restrict__ wq,
             const float* __restrict__ wk, const float* __restrict__ wv,
             const float* __restrict__ wo, const float* __restrict__ waq,
             const float* __restrict__ wak,
             short* __restrict__ xb, short* __restrict__ Wcat,
             short* __restrict__ wob){
  int bid = blockIdx.x;
  const float* src; short* dst; int n, bx;
  if      (bid <  8192){ src=x;   dst=xb;                         n=8388608; bx=bid; }
  else if (bid < 12288){ src=wq;  dst=Wcat;                       n=4194304; bx=bid-8192; }
  else if (bid < 16384){ src=wk;  dst=Wcat+(size_t)2112*2048;     n=4194304; bx=bid-12288; }
  else if (bid < 20480){ src=wv;  dst=Wcat+(size_t)4352*2048;     n=4194304; bx=bid-16384; }
  else if (bid < 24576){ src=wo;  dst=wob;                        n=4194304; bx=bid-20480; }
  else if (bid < 24640){ src=waq; dst=Wcat+(size_t)2048*2048;     n=65536;   bx=bid-24576; }
  else if (bid < 24704){ src=wak; dst=Wcat+(size_t)2080*2048;     n=65536;   bx=bid-24640; }
  else { // zero pad rows 4160..4351: 384 blocks x 1024 shorts = 393216 exact
    int idx = ((bid-24704)*256 + threadIdx.x)*4;
    short4v z = {0,0,0,0};
    *(short4v*)(Wcat + (size_t)4160*2048 + idx) = z;
    return;
  }
  int idx = (bx*256 + threadIdx.x)*4;
  if (idx >= n) return;
  floatx4 v = *(const floatx4*)(src + idx);
  short4v o;
  o[0]=f2bf(v[0]); o[1]=f2bf(v[1]); o[2]=f2bf(v[2]); o[3]=f2bf(v[3]);
  *(short4v*)(dst + idx) = o;
}

// ------------- fused QKV GEMM: C = X @ Wcat^T, 256x256 tile, pipelined 4-phase ----
// R3 schedule. Counter post-mortem (R11): this kernel is LDS-READ-PIPE bound
// (192 ds_read_b128/tile ~ 2300cy + 1250cy conflicts vs 620cy MFMA); all four
// schedule variants plateau 130-164us. Any 8-wave split reads the same 192KB
// LDS per tile; more acc-reuse busts the register file. Near structural floor.
__global__ __launch_bounds__(512,2)
void gemm_qkv(const short* __restrict__ A, const short* __restrict__ B,
              short* __restrict__ Cout, short* __restrict__ Vt){
  __shared__ short SH[65536];   // 128 KiB
  const int K = 2048;
  int tid = threadIdx.x;
  int wave = tid>>6, lane = tid&63, quad = lane>>4, l16 = lane&15;
  int wm_i = wave>>2, wn_i = wave&3;

  int bid = blockIdx.x;
  int swz = (bid&7)*50 + (bid>>3);      // 8 XCDs x 50 blocks, bijective over 400
  int m0 = (swz & 15)*256;
  int n0 = (swz >> 4)*256;

  int srow = tid>>2;
  int sseg = (tid&3) ^ ((srow ^ (srow>>2)) & 3);
  const short* aS = A + (size_t)(m0 + srow)*K + sseg*8;
  const short* bS = B + (size_t)(n0 + srow)*K + sseg*8;
  int sdst = wave*512;

  int sx   = (l16 ^ (l16>>2)) & 3;
  int aoff = (wm_i*128 + l16)*32 + (quad^sx)*8;
  int boff = (wn_i*64  + l16)*32 + (quad^sx)*8;

  floatx4 acc[8][4] = {};
  short8v afA[8], afB[8], bfA[4], bfB[4];

#define QSTAGE(src, chunk) do{ \
    __builtin_amdgcn_global_load_lds(ASG(src), ASL(&SH[(chunk)+sdst]), 16, 0, 0); \
    __builtin_amdgcn_global_load_lds(ASG((src) + (size_t)128*2048), ASL(&SH[(chunk)+sdst+4096]), 16, 0, 0); \
  }while(0)
#define QBAR  asm volatile("s_barrier" ::: "memory")
#define QW4   asm volatile("s_waitcnt vmcnt(4)" ::: "memory")
#define MFMA_ __builtin_amdgcn_mfma_f32_16x16x32_bf16

  QSTAGE(aS,            0);
  QSTAGE(bS,        32768);
  QSTAGE(aS+32,      8192);
  QSTAGE(bS+32, 32768+8192);
  QW4;
  QBAR;
  #pragma unroll
  for (int mf=0; mf<4; ++mf) afA[mf] = *(short8v*)&SH[0     + mf*512 + aoff];
  #pragma unroll
  for (int nf=0; nf<4; ++nf) bfA[nf] = *(short8v*)&SH[32768 + nf*512 + boff];
  QSTAGE(aS + 64, 16384);   // A0 of tile 1 -> buf1

  for (int t=0; t<32; ++t){
    int buf = t&1, nb = buf^1;
    int A0c = buf*16384,        A1c = A0c+8192;
    int B0c = 32768+buf*16384,  B1c = B0c+8192;
    int A0n = nb*16384,         A1n = A0n+8192;
    int B0n = 32768+nb*16384,   B1n = B0n+8192;
    int kn  = ((t+1)&31)*64;
    int kn2 = ((t+2)&31)*64;

    // P1
    #pragma unroll
    for (int mf=4; mf<8; ++mf) afA[mf] = *(short8v*)&SH[A0c + mf*512 + aoff];
    QSTAGE(bS + kn, B0n);
    QW4;
    QBAR;
    __builtin_amdgcn_s_setprio(1);
    #pragma unroll
    for (int mf=0; mf<4; ++mf)
      #pragma unroll
      for (int nf=0; nf<4; ++nf)
        acc[mf][nf] = MFMA_(afA[mf], bfA[nf], acc[mf][nf], 0,0,0);
    __builtin_amdgcn_s_setprio(0);

    // P2
    #pragma unroll
    for (int mf=0; mf<4; ++mf) afB[mf] = *(short8v*)&SH[A1c + mf*512 + aoff];
    #pragma unroll
    for (int nf=0; nf<4; ++nf) bfB[nf] = *(short8v*)&SH[B1c + nf*512 + boff];
    QSTAGE(aS + kn + 32, A1n);
    QBAR;
    __builtin_amdgcn_s_setprio(1);
    #pragma unroll
    for (int mf=4; mf<8; ++mf)
      #pragma unroll
      for (int nf=0; nf<4; ++nf)
        acc[mf][nf] = MFMA_(afA[mf], bfA[nf], acc[mf][nf], 0,0,0);
    __builtin_amdgcn_s_setprio(0);

    // P3
    #pragma unroll
    for (int mf=4; mf<8; ++mf) afB[mf] = *(short8v*)&SH[A1c + mf*512 + aoff];
    QSTAGE(bS + kn + 32, B1n);
    QW4;
    QBAR;
    __builtin_amdgcn_s_setprio(1);
    #pragma unroll
    for (int mf=0; mf<4; ++mf)
      #pragma unroll
      for (int nf=0; nf<4; ++nf)
        acc[mf][nf] = MFMA_(afB[mf], bfB[nf], acc[mf][nf], 0,0,0);
    __builtin_amdgcn_s_setprio(0);

    // P0
    #pragma unroll
    for (int mf=0; mf<4; ++mf) afA[mf] = *(short8v*)&SH[A0n + mf*512 + aoff];
    #pragma unroll
    for (int nf=0; nf<4; ++nf) bfA[nf] = *(short8v*)&SH[B0n + nf*512 + boff];
    QSTAGE(aS + kn2, A0c);
    QBAR;
    __builtin_amdgcn_s_setprio(1);
    #pragma unroll
    for (int mf=4; mf<8; ++mf)
      #pragma unroll
      for (int nf=0; nf<4; ++nf)
        acc[mf][nf] = MFMA_(afB[mf], bfB[nf], acc[mf][nf], 0,0,0);
    __builtin_amdgcn_s_setprio(0);
  }

  __syncthreads();

  if (n0 < VOFF_){
    #pragma unroll
    for (int mf=0; mf<8; ++mf)
      #pragma unroll
      for (int r=0; r<4; ++r){
        size_t gm = (size_t)(m0 + wm_i*128 + mf*16 + quad*4 + r);
        #pragma unroll
        for (int nf=0; nf<4; ++nf)
          Cout[gm*NW_ + n0 + wn_i*64 + nf*16 + l16] = f2bf(acc[mf][nf][r]);
      }
  } else {
    short* T = SH;
    #pragma unroll
    for (int mf=0; mf<8; ++mf){
      int mb = wm_i*128 + mf*16 + quad*4;
      int mc = mb>>3, mi = mb&7;
      #pragma unroll
      for (int nf=0; nf<4; ++nf){
        int n = wn_i*64 + nf*16 + l16;
        short4v p;
        p[0]=f2bf(acc[mf][nf][0]); p[1]=f2bf(acc[mf][nf][1]);
        p[2]=f2bf(acc[mf][nf][2]); p[3]=f2bf(acc[mf][nf][3]);
        *(short4v*)&T[n*256 + ((mc ^ (n&31))*8) + mi] = p;
      }
    }
    __syncthreads();
    int f = tid>>1, half = tid&1;
    size_t vbase = (size_t)(n0 - VOFF_ + f)*4096 + m0;
    #pragma unroll
    for (int c=0; c<16; ++c){
      int cc = half*16 + c;
      short8v v = *(short8v*)&T[f*256 + ((cc ^ (f&31))*8)];
      *(short8v*)&Vt[vbase + cc*8] = v;
    }
  }
#undef QSTAGE
#undef QBAR
#undef QW4
#undef MFMA_
}

// ------------- O GEMM (m97-style, 128x128) -------------
__global__ __launch_bounds__(256,4)
void gemm_nt_f32(const short* __restrict__ A, const short* __restrict__ B,
                 float* __restrict__ Cout, int M, int N, int K){
  __shared__ short As[128][64];
  __shared__ short Bs[128][64];
  int tid = threadIdx.x;
  int wave = tid>>6, lane = tid&63, quad = lane>>4, l16 = lane&15;
  int l7 = l16&7;
  int m0 = blockIdx.x*128, n0 = blockIdx.y*128;
  int wm = (wave>>1)*64, wn = (wave&1)*64;
  floatx4 acc[4][4] = {};

  int lr = lane>>3;
  int sw = (lane&7) ^ lr;
  const short* Abase = A + (size_t)(m0 + wave*32 + lr)*K + sw*8;
  const short* Bbase = B + (size_t)(n0 + wave*32 + lr)*K + sw*8;

  for (int k0 = 0; k0 < K; k0 += 64){
    __syncthreads();
    #pragma unroll
    for (int i=0;i<4;i++){
      __builtin_amdgcn_global_load_lds(ASG(Abase + (size_t)(i*8)*K + k0),
                                       ASL(&As[wave*32 + i*8][0]), 16, 0, 0);
      __builtin_amdgcn_global_load_lds(ASG(Bbase + (size_t)(i*8)*K + k0),
                                       ASL(&Bs[wave*32 + i*8][0]), 16, 0, 0);
    }
    __syncthreads();
    #pragma unroll
    for (int ks=0; ks<2; ks++){
      short8v af[4], bf[4];
      #pragma unroll
      for (int i=0;i<4;i++) af[i] = *(short8v*)&As[wm + i*16 + l16][((ks*4+quad)^l7)*8];
      #pragma unroll
      for (int j=0;j<4;j++) bf[j] = *(short8v*)&Bs[wn + j*16 + l16][((ks*4+quad)^l7)*8];
      #pragma unroll
      for (int i=0;i<4;i++)
        #pragma unroll
        for (int j=0;j<4;j++)
          acc[i][j] = __builtin_amdgcn_mfma_f32_16x16x32_bf16(af[i], bf[j], acc[i][j], 0,0,0);
    }
  }
  #pragma unroll
  for (int i=0;i<4;i++)
    #pragma unroll
    for (int r=0;r<4;r++){
      int gm = m0 + wm + i*16 + quad*4 + r;
      #pragma unroll
      for (int j=0;j<4;j++){
        int gn = n0 + wn + j*16 + l16;
        Cout[(size_t)gm*N + gn] = acc[i][j][r];
      }
    }
}

// ---------------- RoPE on K (2 pairs/thread, 8B coalesced) ------------------
__global__ __launch_bounds__(256) void rope_k(short* __restrict__ X,
                                              const float* __restrict__ fcos,
                                              const float* __restrict__ fsin){
  int i = blockIdx.x*256 + threadIdx.x;
  int row = i >> 9;
  int p0  = (i & 511)*2;
  int s = row & (S_-1);
  int pp = p0 & 63;
  float c0 = fcos[s*64+pp],   sn0 = fsin[s*64+pp];
  float c1 = fcos[s*64+pp+1], sn1 = fsin[s*64+pp+1];
  size_t a = (size_t)row*NW_ + 2112 + p0*2;
  int2v v = *(int2v*)(X + a);
  float re0 = bf2f((short)(v[0] & 0xffff)), im0 = bf2f((short)(v[0] >> 16));
  float re1 = bf2f((short)(v[1] & 0xffff)), im1 = bf2f((short)(v[1] >> 16));
  int2v o;
  o[0] = ((int)(unsigned short)f2bf(re0*sn0 + im0*c0) << 16) | (unsigned short)f2bf(re0*c0 - im0*sn0);
  o[1] = ((int)(unsigned short)f2bf(re1*sn1 + im1*c1) << 16) | (unsigned short)f2bf(re1*c1 - im1*sn1);
  *(int2v*)(X + a) = o;
}

// ---------------- Flash attention v8: gate fused in-kernel -------------------
// Key insight: gate's mfma(qh, kh_j) produces am[j][r] in EXACTLY the same
// lane/register layout as sacc[j][r] (identical 16q x 16k fragment geometry),
// so the gate multiply is element-aligned: Ps = p * sigmoid(am[j][r]).
// Deletes gate_k's work, 32MB of G write+read traffic, 4 G-loads/strip, and
// the G buffer; costs +4 MFMA + ~32 VALU (sigmoid) per strip. Gate is now f32
// (more accurate than the old bf16 G roundtrip).
__global__ __launch_bounds__(256,2)
void flash_k(const short* __restrict__ Qc, const short* __restrict__ Vt,
             const float* __restrict__ fcos, const float* __restrict__ fsin,
             short* __restrict__ O){
  int h = blockIdx.x, pi = blockIdx.y, b = blockIdx.z;
  int tid = threadIdx.x, wave = tid>>6, lane = tid&63, quad = lane>>4, l16 = lane&15;
  int l7 = l16&7;

  __shared__ short Ks [64][128];     // 16 KB
  __shared__ short Vts[128][64];     // 16 KB
  __shared__ short Ps [4][16][72];   // 9 KB

  const float CS = 1.44269504f * 0.08838834764831845f;  // log2(e)/sqrt(128)
  const float NL2E = -1.44269504f;

  for (int ph = 0; ph < 2; ph++){
    int qt = ph ? pi : 31 - pi;
    int srow = qt*64 + wave*16 + l16;
    size_t qrow = (size_t)(b*2048 + srow);
    short8v qf[4];
    #pragma unroll
    for (int ks=0;ks<4;ks++)
      qf[ks] = *(const short8v*)&Qc[qrow*NW_ + h*128 + ks*32 + quad*8];
    // q-hat fragment for the fused gate (rank-32; same A-frag geometry)
    short8v qh = *(const short8v*)&Qc[qrow*NW_ + 2048 + quad*8];
    // fused RoPE on Q fragments (pairs are lane-local)
    #pragma unroll
    for (int ks=0;ks<4;ks++)
      #pragma unroll
      for (int jj=0;jj<4;jj++){
        float re = bf2f(qf[ks][2*jj]), im = bf2f(qf[ks][2*jj+1]);
        int p = ks*16 + quad*4 + jj;
        float c = fcos[srow*64 + p], sn = fsin[srow*64 + p];
        qf[ks][2*jj]   = f2bf(re*c - im*sn);
        qf[ks][2*jj+1] = f2bf(re*sn + im*c);
      }

    floatx4 oacc[8] = {};
    float lp[4] = {0.f,0.f,0.f,0.f};

    for (int kt=0; kt<=qt; kt++){
      int k0 = kt*64;
      __syncthreads();
      {
        const short* Ksrc = Qc + ((size_t)(b*2048 + k0 + wave*16))*NW_ + 2112 + h*128;
        int r4 = lane>>4, c16 = lane&15;
        #pragma unroll
        for (int j=0;j<4;j++)
          __builtin_amdgcn_global_load_lds(
            ASG(Ksrc + (size_t)(j*4 + r4)*NW_ + ((c16 ^ r4 ^ ((j&1)*4))*8)),
            ASL(&Ks[wave*16 + j*4][0]), 16, 0, 0);
        const short* Vsrc = Vt + ((size_t)(h*128 + wave*32 + (lane>>3)))*4096 + b*2048 + k0
                            + (((lane&7) ^ (lane>>3))*8);
        #pragma unroll
        for (int j=0;j<4;j++)
          __builtin_amdgcn_global_load_lds(
            ASG(Vsrc + (size_t)(j*8)*4096),
            ASL(&Vts[wave*32 + j*8][0]), 16, 0, 0);
      }
      __syncthreads();

      // ---- fused gate: am[j] = qh . kh_j  (same C layout as sacc) ----
      floatx4 am[4];
      #pragma unroll
      for (int j=0;j<4;j++){
        short8v khj = *(const short8v*)&Qc[((size_t)(b*2048 + k0 + j*16 + l16))*NW_ + 2080 + quad*8];
        floatx4 z = {0.f,0.f,0.f,0.f};
        am[j] = __builtin_amdgcn_mfma_f32_16x16x32_bf16(qh, khj, z, 0,0,0);
      }

      // ---- QK^T ----
      floatx4 sacc[4] = {};
      #pragma unroll
      for (int j=0;j<4;j++)
        #pragma unroll
        for (int ks2=0;ks2<4;ks2++){
          short8v kf = *(short8v*)&Ks[j*16+l16][((ks2*4+quad)^l7)*8];
          sacc[j] = __builtin_amdgcn_mfma_f32_16x16x32_bf16(qf[ks2], kf, sacc[j], 0,0,0);
        }

      // ---- mask + exp + gate (f32) ----
      bool diag = (kt == qt);
      int qbase = wave*16 + quad*4;
      float pv0[4], pv1[4], pv2[4], pv3[4];
      #pragma unroll
      for (int r=0;r<4;r++){
        #pragma unroll
        for (int j=0;j<4;j++){
          int kin = j*16 + l16;
          bool keep = !diag || (kin <= qbase + r);
          float p = keep ? __builtin_amdgcn_exp2f(sacc[j][r]*CS) : 0.f;
          lp[r] += p;
          float g = __builtin_amdgcn_rcpf(1.f + __builtin_amdgcn_exp2f(am[j][r]*NL2E));
          float pg = p * g;
          if (j==0) pv0[r]=pg; else if (j==1) pv1[r]=pg; else if (j==2) pv2[r]=pg; else pv3[r]=pg;
        }
      }
      // ---- pack to bf16 via v_cvt_pk -> Ps ----
      #pragma unroll
      for (int r=0;r<4;r++){
        unsigned u01, u23;
        asm("v_cvt_pk_bf16_f32 %0, %1, %2" : "=v"(u01) : "v"(pv0[r]), "v"(pv1[r]));
        asm("v_cvt_pk_bf16_f32 %0, %1, %2" : "=v"(u23) : "v"(pv2[r]), "v"(pv3[r]));
        short* Prow = &Ps[wave][quad*4+r][l16];
        Prow[ 0] = (short)(u01 & 0xffffu);
        Prow[16] = (short)(u01 >> 16);
        Prow[32] = (short)(u23 & 0xffffu);
        Prow[48] = (short)(u23 >> 16);
      }

      // ---- P·V ----
      #pragma unroll
      for (int ks2=0; ks2<2; ks2++){
        short8v pf = *(short8v*)&Ps[wave][l16][ks2*32 + quad*8];
        #pragma unroll
        for (int dt=0; dt<8; dt++){
          short8v vf = *(short8v*)&Vts[dt*16 + l16][((ks2*4+quad)^l7)*8];
          oacc[dt] = __builtin_amdgcn_mfma_f32_16x16x32_bf16(pf, vf, oacc[dt], 0,0,0);
        }
      }
    }

    #pragma unroll
    for (int r=0;r<4;r++)
      #pragma unroll
      for (int off=1; off<16; off<<=1)
        lp[r] += __shfl_xor(lp[r], off, 64);
    #pragma unroll
    for (int r=0;r<4;r++){
      float inv = __builtin_amdgcn_rcpf(lp[r]);
      size_t orow = (size_t)(b*2048 + qt*64 + wave*16 + quad*4 + r);
      #pragma unroll
      for (int dt=0;dt<8;dt++)
        O[orow*2048 + h*128 + dt*16 + l16] = f2bf(oacc[dt][r]*inv);
    }
  }
}

// ---------------- launch (5 dispatches) ----------------
extern "C" void kernel_launch(void* const* d_in, const int* in_sizes, int n_in,
                              void* d_out, int out_size, void* d_ws, size_t ws_size,
                              hipStream_t stream){
  const float* x    = (const float*)d_in[0];
  const float* fcos = (const float*)d_in[2];
  const float* fsin = (const float*)d_in[3];
  const float* wq   = (const float*)d_in[4];
  const float* wk   = (const float*)d_in[5];
  const float* wv   = (const float*)d_in[6];
  const float* wo   = (const float*)d_in[7];
  const float* waq  = (const float*)d_in[8];
  const float* wak  = (const float*)d_in[9];
  float* out = (float*)d_out;

  char* ws = (char*)d_ws;
  size_t off = 0;
  short* xb   = (short*)(ws + off); off += (size_t)4096*2048*2;   // x bf16 (dead after gemm)
  short* Wcat = (short*)(ws + off); off += (size_t)NW_*2048*2;    // fused weights; later O
  short* wob  = (short*)(ws + off); off += (size_t)2048*2048*2;
  short* XQKV = (short*)(ws + off); off += (size_t)4096*NW_*2;    // [Q|qh|kh|K|pad]
  short* Vtb  = (short*)(ws + off); off += (size_t)2048*4096*2;   // V transposed
  short* Ob   = Wcat;  // flash output overlays Wcat (dead after gemm_qkv)

  cvt_all<<<25088,256,0,stream>>>(x, wq, wk, wv, wo, waq, wak, xb, Wcat, wob);

  gemm_qkv<<<dim3(400),512,0,stream>>>(xb, Wcat, XQKV, Vtb);

  rope_k<<<8192,256,0,stream>>>(XQKV, fcos, fsin);

  flash_k<<<dim3(16,16,2),256,0,stream>>>(XQKV, Vtb, fcos, fsin, Ob);

  gemm_nt_f32<<<dim3(32,16),256,0,stream>>>(Ob, wob, out, 4096, 2048, 2048);
}